// Round 4
// baseline (477.153 us; speedup 1.0000x reference)
//
#include <hip/hip_runtime.h>

typedef _Float16 f16;
typedef _Float16 f16x8 __attribute__((ext_vector_type(8)));
typedef float f32x4 __attribute__((ext_vector_type(4)));

#define T_STEPS 256
#define F_IN 32
#define G3 768  // 3*H

#define MF(a, b, c) __builtin_amdgcn_mfma_f32_16x16x32_f16((a), (b), (c), 0, 0, 0)

// d_ws layout:
//   WrP: [48 ntiles][8 kfrags][64 lanes] f16x8 = 384 KB  (rec_kernel fragments)
//   WkP: [48 ntiles][64 lanes] f16x8           =  48 KB  (input kernel fragments)
// Fragment convention (A and B identical, permutation cancels in MFMA):
//   lane l, elem e -> k = (l>>4)*8 + e (within 32-wide kfrag), n = ntile*16 + (l&15)
__global__ void pack_weights_kernel(const float* __restrict__ wk,
                                    const float* __restrict__ wr,
                                    f16x8* __restrict__ wrp,
                                    f16x8* __restrict__ wkp) {
    const int bid = blockIdx.x;
    const int l = threadIdx.x;
    const int lr = l & 15, lq = l >> 4;
    if (bid < 384) {
        const int nt = bid >> 3, kf = bid & 7;
        const int n = nt * 16 + lr;
        f16x8 v;
#pragma unroll
        for (int e = 0; e < 8; ++e) {
            const int k = kf * 32 + lq * 8 + e;
            v[e] = (f16)wr[k * G3 + n];
        }
        wrp[bid * 64 + l] = v;
    } else {
        const int nt = bid - 384;
        const int n = nt * 16 + lr;
        f16x8 v;
#pragma unroll
        for (int e = 0; e < 8; ++e) {
            const int k = lq * 8 + e;
            v[e] = (f16)wk[k * G3 + n];
        }
        wkp[nt * 64 + l] = v;
    }
}

// hbuf: [2 buffers][16 rows][256 cols] f16, row = 512 B, XOR-swizzled:
//   byte_in_row ^= ((row&7)<<4)  -> ds_read_b128 fragments are bank-conflict-free,
//   scattered b16 writes <=2-way. Buffer 1 at +8192 B (immediate offset).
#define HRD(hc, kf)                                                            \
    (*(const f16x8*)((const char*)(hc) + lr * 512 +                            \
                     ((((kf) * 64) | (lq * 16)) ^ ((lr & 7) << 4))))

__global__ __launch_bounds__(512, 2) void gru_fused_kernel(
    const float* __restrict__ x,      // [2048][256][32]
    const float* __restrict__ bias,   // [2][768]
    const float* __restrict__ gamma,
    const float* __restrict__ beta,
    const float* __restrict__ mmean,
    const float* __restrict__ mvar,
    const float* __restrict__ dw,     // [256]
    const float* __restrict__ db,     // [1]
    const f16x8* __restrict__ wrp,
    const f16x8* __restrict__ wkp,
    float* __restrict__ out)          // [2048]
{
    __shared__ __align__(16) f16 hbuf[2][16 * 256];  // 16 KB, swizzled
    __shared__ __align__(16) f16 xbuf[2][16 * 32];   // 2 KB
    __shared__ f16x8 wkl[48 * 64];                   // 48 KB input-proj frags
    __shared__ f16x8 wl5[8][8][64];                  // 64 KB hh1 tile per wave
    __shared__ float red[8][16];

    const int tid = threadIdx.x;
    const int w = tid >> 6;
    const int l = tid & 63;
    const int lr = l & 15;
    const int lq = l >> 4;
    const int r0 = blockIdx.x * 16;

    const int nt0 = 2 * w, nt1 = 2 * w + 1;
    const int nt2 = 16 + 2 * w, nt3 = 17 + 2 * w;
    const int nt4 = 32 + 2 * w, nt5 = 33 + 2 * w;

    // ---- 5 weight tiles -> registers/AGPR, hh1 tile -> LDS ----
    f16x8 W[5][8];
    {
        const int ntr[5] = {nt0, nt1, nt2, nt3, nt4};
#pragma unroll
        for (int i = 0; i < 5; ++i)
#pragma unroll
            for (int kf = 0; kf < 8; ++kf)
                W[i][kf] = wrp[((size_t)ntr[i] * 8 + kf) * 64 + l];
    }
#pragma unroll
    for (int kf = 0; kf < 8; ++kf)
        wl5[w][kf][l] = wrp[((size_t)nt5 * 8 + kf) * 64 + l];

    for (int i = tid; i < 48 * 64; i += 512) wkl[i] = wkp[i];

    // per-lane biases (col j = 32w + 16g + lr); z/r negated for exp(-x)
    float nbz0, nbz1, nbr0, nbr1, bxh0, bxh1, brh0, brh1;
    {
        const int j0 = 32 * w + lr, j1 = j0 + 16;
        nbz0 = -(bias[j0] + bias[G3 + j0]);
        nbz1 = -(bias[j1] + bias[G3 + j1]);
        nbr0 = -(bias[256 + j0] + bias[G3 + 256 + j0]);
        nbr1 = -(bias[256 + j1] + bias[G3 + 256 + j1]);
        bxh0 = bias[512 + j0];
        bxh1 = bias[512 + j1];
        brh0 = bias[G3 + 512 + j0];
        brh1 = bias[G3 + 512 + j1];
    }

    // zero h(0); swizzle is bijective so plain zero fill is fine
    {
        f16x8 z8 = {0, 0, 0, 0, 0, 0, 0, 0};
        ((f16x8*)hbuf[0])[tid] = z8;  // 512 * 16 B = 8 KB exactly
    }

    const int xrow = tid >> 5, xf = tid & 31;
    const float* xptr = x + ((size_t)(r0 + xrow) * T_STEPS) * F_IN + xf;
    xbuf[0][xrow * 32 + xf] = (f16)xptr[0];
    float xv = xptr[F_IN];  // x at t=1

    f32x4 hr0 = {0.f, 0.f, 0.f, 0.f};
    f32x4 hr1 = {0.f, 0.f, 0.f, 0.f};
    const f32x4 fz = {0.f, 0.f, 0.f, 0.f};

    __syncthreads();

    // One GRU step with compile-time buffer parity: all LDS addresses are
    // loop-invariant (LICM -> persistent VGPRs, zero per-step address VALU).
#define GRU_STEP(CUR, t)                                                       \
    {                                                                          \
        const f16* hc = hbuf[CUR];                                             \
        f16* hw = hbuf[CUR ^ 1];                                               \
        xbuf[CUR ^ 1][xrow * 32 + xf] = (f16)xv;                               \
        {                                                                      \
            const int tn = ((t) + 2 < T_STEPS) ? ((t) + 2) : (T_STEPS - 1);    \
            xv = xptr[(size_t)tn * F_IN];                                      \
        }                                                                      \
        const f16x8 ax = *(const f16x8*)&xbuf[CUR][lr * 32 + lq * 8];          \
        f32x4 az0 = MF(ax, wkl[nt0 * 64 + l], fz);                             \
        f32x4 az1 = MF(ax, wkl[nt1 * 64 + l], fz);                             \
        f32x4 ar0 = MF(ax, wkl[nt2 * 64 + l], fz);                             \
        f32x4 ar1 = MF(ax, wkl[nt3 * 64 + l], fz);                             \
        f32x4 axh0 = MF(ax, wkl[nt4 * 64 + l], fz);                            \
        f32x4 axh1 = MF(ax, wkl[nt5 * 64 + l], fz);                            \
        f32x4 arh0 = fz, arh1 = fz;                                            \
        _Pragma("unroll") for (int kf = 0; kf < 8; ++kf) {                     \
            const f16x8 ah = HRD(hc, kf);                                      \
            const f16x8 w5 = wl5[w][kf][l];                                    \
            az0 = MF(ah, W[0][kf], az0);                                       \
            az1 = MF(ah, W[1][kf], az1);                                       \
            ar0 = MF(ah, W[2][kf], ar0);                                       \
            ar1 = MF(ah, W[3][kf], ar1);                                       \
            arh0 = MF(ah, W[4][kf], arh0);                                     \
            arh1 = MF(ah, w5, arh1);                                           \
        }                                                                      \
        _Pragma("unroll") for (int gg = 0; gg < 4; ++gg) {                     \
            const int m = lq * 4 + gg;                                         \
            {                                                                  \
                const float z = __builtin_amdgcn_rcpf(1.f + __expf(nbz0 - az0[gg])); \
                const float rr = __builtin_amdgcn_rcpf(1.f + __expf(nbr0 - ar0[gg])); \
                const float hh = fmaxf(0.f, fmaf(rr, arh0[gg] + brh0, axh0[gg] + bxh0)); \
                const float hn = fmaf(z, hr0[gg] - hh, hh);                    \
                hr0[gg] = hn;                                                  \
                *(f16*)((char*)hw + m * 512 +                                  \
                        ((64 * w + 2 * lr) ^ ((m & 7) << 4))) = (f16)hn;       \
            }                                                                  \
            {                                                                  \
                const float z = __builtin_amdgcn_rcpf(1.f + __expf(nbz1 - az1[gg])); \
                const float rr = __builtin_amdgcn_rcpf(1.f + __expf(nbr1 - ar1[gg])); \
                const float hh = fmaxf(0.f, fmaf(rr, arh1[gg] + brh1, axh1[gg] + bxh1)); \
                const float hn = fmaf(z, hr1[gg] - hh, hh);                    \
                hr1[gg] = hn;                                                  \
                *(f16*)((char*)hw + m * 512 +                                  \
                        ((64 * w + 32 + 2 * lr) ^ ((m & 7) << 4))) = (f16)hn;  \
            }                                                                  \
        }                                                                      \
        __syncthreads();                                                       \
    }

#pragma unroll 1
    for (int tt = 0; tt < T_STEPS / 2; ++tt) {
        GRU_STEP(0, 2 * tt);
        GRU_STEP(1, 2 * tt + 1);
    }
#undef GRU_STEP

    // epilogue: BatchNorm (inference) + Dense(1), deterministic reduction
    float s[4] = {0.f, 0.f, 0.f, 0.f};
    {
        const int j0 = 32 * w + lr, j1 = j0 + 16;
        const float sc0 = gamma[j0] * rsqrtf(mvar[j0] + 1e-3f);
        const float sc1 = gamma[j1] * rsqrtf(mvar[j1] + 1e-3f);
        const float mn0 = mmean[j0], mn1 = mmean[j1];
        const float bt0 = beta[j0], bt1 = beta[j1];
        const float wv0 = dw[j0], wv1 = dw[j1];
#pragma unroll
        for (int gg = 0; gg < 4; ++gg) {
            s[gg] += ((hr0[gg] - mn0) * sc0 + bt0) * wv0;
            s[gg] += ((hr1[gg] - mn1) * sc1 + bt1) * wv1;
        }
    }
#pragma unroll
    for (int mask = 1; mask <= 8; mask <<= 1) {
#pragma unroll
        for (int gg = 0; gg < 4; ++gg) s[gg] += __shfl_xor(s[gg], mask, 64);
    }
    if (lr == 0) {
#pragma unroll
        for (int gg = 0; gg < 4; ++gg) red[w][lq * 4 + gg] = s[gg];
    }
    __syncthreads();
    if (tid < 16) {
        float o = db[0];
#pragma unroll
        for (int ww = 0; ww < 8; ++ww) o += red[ww][tid];
        out[r0 + tid] = o;
    }
}

extern "C" void kernel_launch(void* const* d_in, const int* in_sizes, int n_in,
                              void* d_out, int out_size, void* d_ws, size_t ws_size,
                              hipStream_t stream) {
    const float* x      = (const float*)d_in[0];
    const float* kern   = (const float*)d_in[1];
    const float* rkern  = (const float*)d_in[2];
    const float* bias   = (const float*)d_in[3];
    const float* gamma  = (const float*)d_in[4];
    const float* beta   = (const float*)d_in[5];
    const float* mmean  = (const float*)d_in[6];
    const float* mvar   = (const float*)d_in[7];
    const float* dw     = (const float*)d_in[8];
    const float* db     = (const float*)d_in[9];
    float* out = (float*)d_out;

    f16x8* wrp = (f16x8*)d_ws;        // 384 KB
    f16x8* wkp = wrp + 48 * 8 * 64;   //  48 KB after

    pack_weights_kernel<<<432, 64, 0, stream>>>(kern, rkern, wrp, wkp);
    gru_fused_kernel<<<128, 512, 0, stream>>>(x, bias, gamma, beta, mmean, mvar,
                                              dw, db, wrp, wkp, out);
}

// Round 6
// 446.244 us; speedup vs baseline: 1.0693x; 1.0693x over previous
//
#include <hip/hip_runtime.h>

typedef _Float16 f16;
typedef _Float16 f16x8 __attribute__((ext_vector_type(8)));
typedef float f32x4 __attribute__((ext_vector_type(4)));

#define T_STEPS 256
#define F_IN 32
#define G3 768

#define MF(a, b, c) __builtin_amdgcn_mfma_f32_16x16x32_f16((a), (b), (c), 0, 0, 0)

// d_ws: WrP [48 nt][8 kf][64 lanes] f16x8 (384 KB) ; WkP [48 nt][64 lanes] (48 KB)
// Fragment convention: lane l, elem e -> k = (l>>4)*8 + e, n = nt*16 + (l&15)
__global__ void pack_weights_kernel(const float* __restrict__ wk,
                                    const float* __restrict__ wr,
                                    f16x8* __restrict__ wrp,
                                    f16x8* __restrict__ wkp) {
    const int bid = blockIdx.x;
    const int l = threadIdx.x;
    const int lr = l & 15, lq = l >> 4;
    if (bid < 384) {
        const int nt = bid >> 3, kf = bid & 7;
        const int n = nt * 16 + lr;
        f16x8 v;
#pragma unroll
        for (int e = 0; e < 8; ++e) v[e] = (f16)wr[(kf * 32 + lq * 8 + e) * G3 + n];
        wrp[bid * 64 + l] = v;
    } else {
        const int nt = bid - 384;
        const int n = nt * 16 + lr;
        f16x8 v;
#pragma unroll
        for (int e = 0; e < 8; ++e) v[e] = (f16)wk[(lq * 8 + e) * G3 + n];
        wkp[nt * 64 + l] = v;
    }
}

// hbuf storage (verified by element trace + bank analysis):
//   element (row r, col j): kf=j>>5, c=(j>>3)&3, e=j&7 stored at byte
//   kf*1024 + r*64 + ((c ^ ((r>>2)&3))<<4) + e*2
// Reads per kfrag: 64 lanes cover a contiguous 1024 B block bijectively in
// 16 B chunks -> canonical conflict-free. Writes: ^lq slot swizzle spreads the
// 4 lq groups to distinct banks; residual 2-way (b16 pairs in a dword) is free.
__global__ __launch_bounds__(512, 2) void gru_fused_kernel(
    const float* __restrict__ x,      // [2048][256][32]
    const float* __restrict__ bias,   // [2][768]
    const float* __restrict__ gamma,
    const float* __restrict__ beta,
    const float* __restrict__ mmean,
    const float* __restrict__ mvar,
    const float* __restrict__ dw,     // [256]
    const float* __restrict__ db,     // [1]
    const f16x8* __restrict__ wrp,
    const f16x8* __restrict__ wkp,
    float* __restrict__ out)          // [2048]
{
    __shared__ __align__(16) char hbuf_raw[2 * 8192];  // ping-pong h, 16 KB
    __shared__ __align__(16) char xbuf_raw[2 * 1024];  // ping-pong x_t, 2 KB
    __shared__ f16x8 wkl[48 * 64];                     // input-proj frags, 48 KB
    __shared__ f16x8 wl5[8][8][64];                    // hh1 tile per wave, 64 KB
    __shared__ float red[8][16];

    const int tid = threadIdx.x;
    const int w = tid >> 6;
    const int l = tid & 63;
    const int lr = l & 15;
    const int lq = l >> 4;
    const int r0 = blockIdx.x * 16;

    const int nt0 = 2 * w, nt1 = 2 * w + 1;
    const int nt2 = 16 + 2 * w, nt3 = 17 + 2 * w;
    const int nt4 = 32 + 2 * w, nt5 = 33 + 2 * w;

    // ---- 5 weight tiles -> registers/AGPR (builtin loads, r3-proven) ----
    f16x8 W[5][8];
    {
        const int ntr[5] = {nt0, nt1, nt2, nt3, nt4};
#pragma unroll
        for (int i = 0; i < 5; ++i)
#pragma unroll
            for (int kf = 0; kf < 8; ++kf)
                W[i][kf] = wrp[((size_t)ntr[i] * 8 + kf) * 64 + l];
    }
#pragma unroll
    for (int kf = 0; kf < 8; ++kf)
        wl5[w][kf][l] = wrp[((size_t)nt5 * 8 + kf) * 64 + l];

    for (int i = tid; i < 48 * 64; i += 512) wkl[i] = wkp[i];

    float nbz0, nbz1, nbr0, nbr1, bxh0, bxh1, brh0, brh1;
    {
        const int j0 = 32 * w + lr, j1 = j0 + 16;
        nbz0 = -(bias[j0] + bias[G3 + j0]);
        nbz1 = -(bias[j1] + bias[G3 + j1]);
        nbr0 = -(bias[256 + j0] + bias[G3 + 256 + j0]);
        nbr1 = -(bias[256 + j1] + bias[G3 + 256 + j1]);
        bxh0 = bias[512 + j0];
        bxh1 = bias[512 + j1];
        brh0 = bias[G3 + 512 + j0];
        brh1 = bias[G3 + 512 + j1];
    }

    {   // zero h(0): buffer 0 (8192 B = 512 threads x 16 B)
        f16x8 z8 = {0, 0, 0, 0, 0, 0, 0, 0};
        ((f16x8*)hbuf_raw)[tid] = z8;
    }

    const int xrow = tid >> 5, xf = tid & 31;
    const float* xptr = x + ((size_t)(r0 + xrow) * T_STEPS) * F_IN + xf;
    *(f16*)(xbuf_raw + xrow * 64 + xf * 2) = (f16)xptr[0];
    float xv = xptr[F_IN];  // x at t=1

    // loop-invariant LDS byte offsets
    const int rdoff = lr * 64 + (((lq ^ (lr >> 2)) & 3) << 4);
    const int wb0 = w * 1024 + lq * 256 + ((((lr >> 3) ^ lq) & 3) << 4) + (lr & 7) * 2;
    const int wb1 = w * 1024 + lq * 256 + ((((2 + (lr >> 3)) ^ lq) & 3) << 4) + (lr & 7) * 2;

    float hr0[4] = {0.f, 0.f, 0.f, 0.f};
    float hr1[4] = {0.f, 0.f, 0.f, 0.f};
    const f32x4 fz = {0.f, 0.f, 0.f, 0.f};

    int bufsel = 0, xsel = 0;

    __syncthreads();

#define GATES(azv, arv, arhv, axhv, nbz_, nbr_, bxh_, brh_, hra, wb_)            \
    _Pragma("unroll") for (int gg = 0; gg < 4; ++gg) {                           \
        const float zz = __builtin_amdgcn_rcpf(1.f + __expf(nbz_ - azv[gg]));    \
        const float rr = __builtin_amdgcn_rcpf(1.f + __expf(nbr_ - arv[gg]));    \
        const float hh = fmaxf(0.f, fmaf(rr, arhv[gg] + brh_, axhv[gg] + bxh_)); \
        const float hn = fmaf(zz, hra[gg] - hh, hh);                             \
        hra[gg] = hn;                                                            \
        *(f16*)(hw + wb_ + gg * 64) = (f16)hn;                                   \
    }

#pragma unroll 1
    for (int t = 0; t < T_STEPS; ++t) {
        const char* hb = hbuf_raw + bufsel;
        char* hw = hbuf_raw + (bufsel ^ 8192);
        const char* xbr = xbuf_raw + xsel;
        char* xbw = xbuf_raw + (xsel ^ 1024);

        // publish x for t+1 into nxt buffer (no reader this iter), prefetch t+2
        *(f16*)(xbw + xrow * 64 + xf * 2) = (f16)xv;
        {
            const int tn = (t + 2 < T_STEPS) ? (t + 2) : (T_STEPS - 1);
            xv = xptr[(size_t)tn * F_IN];
        }

        const f16x8 ax = *(const f16x8*)(xbr + lr * 64 + lq * 16);

        // input projection: 6 MFMA (K=32)
        f32x4 az0 = MF(ax, wkl[nt0 * 64 + l], fz);
        f32x4 az1 = MF(ax, wkl[nt1 * 64 + l], fz);
        f32x4 ar0 = MF(ax, wkl[nt2 * 64 + l], fz);
        f32x4 ar1 = MF(ax, wkl[nt3 * 64 + l], fz);
        f32x4 axh0 = MF(ax, wkl[nt4 * 64 + l], fz);
        f32x4 axh1 = MF(ax, wkl[nt5 * 64 + l], fz);
        f32x4 arh0 = fz, arh1 = fz;

        // recurrent matmul: kf outer, each ah frag read once, 6 indep chains
#pragma unroll
        for (int kf = 0; kf < 8; ++kf) {
            const f16x8 ah = *(const f16x8*)(hb + rdoff + kf * 1024);
            const f16x8 w5 = wl5[w][kf][l];
            az0 = MF(ah, W[0][kf], az0);
            az1 = MF(ah, W[1][kf], az1);
            ar0 = MF(ah, W[2][kf], ar0);
            ar1 = MF(ah, W[3][kf], ar1);
            arh0 = MF(ah, W[4][kf], arh0);
            arh1 = MF(ah, w5, arh1);
        }

        GATES(az0, ar0, arh0, axh0, nbz0, nbr0, bxh0, brh0, hr0, wb0);
        GATES(az1, ar1, arh1, axh1, nbz1, nbr1, bxh1, brh1, hr1, wb1);

        bufsel ^= 8192;
        xsel ^= 1024;
        __syncthreads();
    }
#undef GATES

    // epilogue: BatchNorm (inference) + Dense(1), deterministic reduction
    float s[4] = {0.f, 0.f, 0.f, 0.f};
    {
        const int j0 = 32 * w + lr, j1 = j0 + 16;
        const float sc0 = gamma[j0] * rsqrtf(mvar[j0] + 1e-3f);
        const float sc1 = gamma[j1] * rsqrtf(mvar[j1] + 1e-3f);
        const float mn0 = mmean[j0], mn1 = mmean[j1];
        const float bt0 = beta[j0], bt1 = beta[j1];
        const float wv0 = dw[j0], wv1 = dw[j1];
#pragma unroll
        for (int gg = 0; gg < 4; ++gg) {
            s[gg] += ((hr0[gg] - mn0) * sc0 + bt0) * wv0;
            s[gg] += ((hr1[gg] - mn1) * sc1 + bt1) * wv1;
        }
    }
#pragma unroll
    for (int mask = 1; mask <= 8; mask <<= 1) {
#pragma unroll
        for (int gg = 0; gg < 4; ++gg) s[gg] += __shfl_xor(s[gg], mask, 64);
    }
    if (lr == 0) {
#pragma unroll
        for (int gg = 0; gg < 4; ++gg) red[w][lq * 4 + gg] = s[gg];
    }
    __syncthreads();
    if (tid < 16) {
        float o = db[0];
#pragma unroll
        for (int ww = 0; ww < 8; ++ww) o += red[ww][tid];
        out[r0 + tid] = o;
    }
}

extern "C" void kernel_launch(void* const* d_in, const int* in_sizes, int n_in,
                              void* d_out, int out_size, void* d_ws, size_t ws_size,
                              hipStream_t stream) {
    const float* x      = (const float*)d_in[0];
    const float* kern   = (const float*)d_in[1];
    const float* rkern  = (const float*)d_in[2];
    const float* bias   = (const float*)d_in[3];
    const float* gamma  = (const float*)d_in[4];
    const float* beta   = (const float*)d_in[5];
    const float* mmean  = (const float*)d_in[6];
    const float* mvar   = (const float*)d_in[7];
    const float* dw     = (const float*)d_in[8];
    const float* db     = (const float*)d_in[9];
    float* out = (float*)d_out;

    f16x8* wrp = (f16x8*)d_ws;        // 384 KB
    f16x8* wkp = wrp + 48 * 8 * 64;   //  48 KB after

    pack_weights_kernel<<<432, 64, 0, stream>>>(kern, rkern, wrp, wkp);
    gru_fused_kernel<<<128, 512, 0, stream>>>(x, bias, gamma, beta, mmean, mvar,
                                              dw, db, wrp, wkp, out);
}